// Round 6
// baseline (269.734 us; speedup 1.0000x reference)
//
#include <hip/hip_runtime.h>
#include <hip/hip_bf16.h>
#include <stdint.h>

typedef __attribute__((ext_vector_type(8))) short s16x8;
typedef __attribute__((ext_vector_type(4))) float f32x4;

__device__ __forceinline__ unsigned short f32_bf16(float f) {
  union { float f; uint32_t u; } v; v.f = f;
  return (unsigned short)((v.u + 0x7FFFu + ((v.u >> 16) & 1u)) >> 16);
}

__device__ __forceinline__ uint32_t pack_bf16(float lo, float hi) {
  __hip_bfloat162 h = __float22bfloat162_rn(float2{lo, hi});
  union { __hip_bfloat162 h; uint32_t u; } u; u.h = h; return u.u;
}

// Exchange 4-row chunks across the four 16-lane groups to build an MFMA
// A-fragment (k = 8*l4 + j) from C-fragment-resident data (lane = row).
__device__ __forceinline__ s16x8 xchg(uint32_t lo0, uint32_t lo1,
                                      uint32_t hi0, uint32_t hi1,
                                      int srcA, int srcB, uint32_t hisel) {
  int a0 = __shfl((int)lo0, srcA), b0 = __shfl((int)hi0, srcA);
  int a1 = __shfl((int)lo1, srcA), b1 = __shfl((int)hi1, srcA);
  int a2 = __shfl((int)lo0, srcB), b2 = __shfl((int)hi0, srcB);
  int a3 = __shfl((int)lo1, srcB), b3 = __shfl((int)hi1, srcB);
  union { uint32_t u[4]; s16x8 v; } r;
  r.u[0] = hisel ? (uint32_t)b0 : (uint32_t)a0;
  r.u[1] = hisel ? (uint32_t)b1 : (uint32_t)a1;
  r.u[2] = hisel ? (uint32_t)b2 : (uint32_t)a2;
  r.u[3] = hisel ? (uint32_t)b3 : (uint32_t)a3;
  return r.v;
}

// ---------------- kernel 1: weights f32 -> bf16 ----------------
__global__ void convert_w(const float* __restrict__ wqkv,
                          const float* __restrict__ wout,
                          unsigned short* __restrict__ o) {
  int i = blockIdx.x * 256 + threadIdx.x;           // 262144 total
  if (i < 768 * 256) o[i] = f32_bf16(wqkv[i]);
  else               o[i] = f32_bf16(wout[i - 768 * 256]);
}

// ------- kernel 2: fused QKV + attention + out-projection, per group -----
// 1024 threads = 16 waves; wave (h = w>>1, s = w&1) produces q/k/v for
// tokens [32s,32s+32) of head h, all routed through per-head LDS buffers
// with 16B-slot XOR swizzles so fragments read back as single b128 ops.
// Cross-phase register state ~0 -> fits the 128-reg/wave cap of a
// 1024-thread block (4 waves/SIMD resident).
__global__ __launch_bounds__(1024) void mha_fused(
    const float* __restrict__ x,
    const unsigned short* __restrict__ wqkv,   // [768][256] bf16
    const unsigned short* __restrict__ wout,   // [256][256] bf16
    const float* __restrict__ bias,            // [256] f32
    float* __restrict__ out) {                 // [N][256] f32
  __shared__ unsigned short xt[64 * 256];      // 32 KB: x tile, later attn-out
  __shared__ unsigned short qkb[8][64 * 64];   // 64 KB: per head [tok][d'] q:0-31 k:32-63
  __shared__ unsigned short vtb[8][32 * 64];   // 32 KB: per head v^T [d][tok]

  const int g    = blockIdx.x;
  const int tid  = threadIdx.x;
  const int w    = tid >> 6;
  const int lane = tid & 63;
  const int l15  = lane & 15;
  const int l4   = lane >> 4;
  const int h    = w >> 1;
  const int s    = w & 1;

  // ---- stage x (64x256 f32 -> bf16, 16B-slot swizzled rows) ----
  {
    const int row = tid >> 4;
    const int c0  = (tid & 15) * 16;
    const float* src = x + (size_t)(g * 64 + row) * 256 + c0;
    const uint32_t rsw = (uint32_t)(row & 7) << 4;
    float4 f0 = *(const float4*)(src);
    float4 f1 = *(const float4*)(src + 4);
    float4 f2 = *(const float4*)(src + 8);
    float4 f3 = *(const float4*)(src + 12);
    uint32_t b0 = ((uint32_t)(row * 512 + c0 * 2)) ^ rsw;
    uint32_t b1 = ((uint32_t)(row * 512 + c0 * 2 + 16)) ^ rsw;
    *(uint4*)((char*)xt + b0) =
        make_uint4(pack_bf16(f0.x, f0.y), pack_bf16(f0.z, f0.w),
                   pack_bf16(f1.x, f1.y), pack_bf16(f1.z, f1.w));
    *(uint4*)((char*)xt + b1) =
        make_uint4(pack_bf16(f2.x, f2.y), pack_bf16(f2.z, f2.w),
                   pack_bf16(f3.x, f3.y), pack_bf16(f3.z, f3.w));
  }
  __syncthreads();

  const uint32_t xsw   = (uint32_t)(l15 & 7) << 4;
  const int      srcA  = l15 + ((lane & 16) << 1);  // l15 + 32*(l4&1)
  const int      srcB  = srcA + 16;
  const uint32_t hisel = (uint32_t)(lane & 32);

  unsigned short* qkh = qkb[h];
  unsigned short* vth = vtb[h];

  // ---- QKV production for this wave's 32 tokens (single x pass) ----
  {
    f32x4 qT[2][2], kT[2][2], vv[2][2];
#pragma unroll
    for (int t = 0; t < 2; ++t)
#pragma unroll
      for (int m = 0; m < 2; ++m) {
        qT[t][m] = (f32x4){0.f, 0.f, 0.f, 0.f};
        kT[t][m] = (f32x4){0.f, 0.f, 0.f, 0.f};
        vv[t][m] = (f32x4){0.f, 0.f, 0.f, 0.f};
      }
    const unsigned short* wbase = wqkv + (size_t)(h * 32 + l15) * 256 + l4 * 8;
    for (int kk = 0; kk < 8; ++kk) {
      s16x8 a[2];
#pragma unroll
      for (int m2 = 0; m2 < 2; ++m2) {
        int tok = 16 * (2 * s + m2) + l15;
        uint32_t byte = ((uint32_t)(tok * 512 + kk * 64 + l4 * 16)) ^ xsw;
        a[m2] = *(const s16x8*)((const char*)xt + byte);
      }
#pragma unroll
      for (int t = 0; t < 2; ++t) {
        s16x8 wq = *(const s16x8*)(wbase + (size_t)(16 * t) * 256 + kk * 32);
        s16x8 wk = *(const s16x8*)(wbase + (size_t)(256 + 16 * t) * 256 + kk * 32);
        s16x8 wv = *(const s16x8*)(wbase + (size_t)(512 + 16 * t) * 256 + kk * 32);
#pragma unroll
        for (int m2 = 0; m2 < 2; ++m2) {
          qT[t][m2] = __builtin_amdgcn_mfma_f32_16x16x32_bf16(wq, a[m2], qT[t][m2], 0, 0, 0);
          kT[t][m2] = __builtin_amdgcn_mfma_f32_16x16x32_bf16(wk, a[m2], kT[t][m2], 0, 0, 0);
          vv[t][m2] = __builtin_amdgcn_mfma_f32_16x16x32_bf16(a[m2], wv, vv[t][m2], 0, 0, 0);
        }
      }
    }
    // write q,k: C-frag (col=tok=l15, row=d=16t+4*l4+r) -> qkh[tok][d'] b64
#pragma unroll
    for (int t = 0; t < 2; ++t)
#pragma unroll
      for (int m2 = 0; m2 < 2; ++m2) {
        int tok = 16 * (2 * s + m2) + l15;
        uint32_t slq = (uint32_t)((2 * t + (l4 >> 1)) ^ (tok & 7)) << 4;
        uint32_t slk = (uint32_t)((4 + 2 * t + (l4 >> 1)) ^ (tok & 7)) << 4;
        uint32_t base = (uint32_t)(tok * 128) + (uint32_t)(l4 & 1) * 8;
        *(uint2*)((char*)qkh + (base + slq)) =
            make_uint2(pack_bf16(qT[t][m2][0], qT[t][m2][1]),
                       pack_bf16(qT[t][m2][2], qT[t][m2][3]));
        *(uint2*)((char*)qkh + (base + slk)) =
            make_uint2(pack_bf16(kT[t][m2][0], kT[t][m2][1]),
                       pack_bf16(kT[t][m2][2], kT[t][m2][3]));
      }
    // write v^T: C-frag (col=d=16t+l15, row=tok=16*(2s+m2)+4*l4+r) -> vth[d][tok]
#pragma unroll
    for (int t = 0; t < 2; ++t)
#pragma unroll
      for (int m2 = 0; m2 < 2; ++m2) {
        int d = 16 * t + l15;
        uint32_t sl = (uint32_t)((2 * (2 * s + m2) + (l4 >> 1)) ^ (d & 7)) << 4;
        uint32_t byte = (uint32_t)(d * 128) + sl + (uint32_t)(l4 & 1) * 8;
        *(uint2*)((char*)vth + byte) =
            make_uint2(pack_bf16(vv[t][m2][0], vv[t][m2][1]),
                       pack_bf16(vv[t][m2][2], vv[t][m2][3]));
      }
  }
  __syncthreads();

  // ---- attention: energy^T -> softmax -> PV, o into xt ----
  {
    s16x8 kA[4], qB[2], vB[2][2];
#pragma unroll
    for (int mb = 0; mb < 4; ++mb) {
      int tok = 16 * mb + l15;
      uint32_t byte = (uint32_t)(tok * 128) + ((uint32_t)((4 + l4) ^ (tok & 7)) << 4);
      kA[mb] = *(const s16x8*)((const char*)qkh + byte);
    }
#pragma unroll
    for (int nb = 0; nb < 2; ++nb) {
      int tok = 16 * (2 * s + nb) + l15;
      uint32_t byte = (uint32_t)(tok * 128) + ((uint32_t)(l4 ^ (tok & 7)) << 4);
      qB[nb] = *(const s16x8*)((const char*)qkh + byte);
    }
#pragma unroll
    for (int kk2 = 0; kk2 < 2; ++kk2)
#pragma unroll
      for (int t = 0; t < 2; ++t) {
        int d = 16 * t + l15;
        uint32_t byte = (uint32_t)(d * 128) + ((uint32_t)((4 * kk2 + l4) ^ (d & 7)) << 4);
        vB[kk2][t] = *(const s16x8*)((const char*)vth + byte);
      }

#pragma unroll
    for (int nb = 0; nb < 2; ++nb) {
      f32x4 en[4];
#pragma unroll
      for (int mb = 0; mb < 4; ++mb) {
        en[mb] = (f32x4){0.f, 0.f, 0.f, 0.f};
        en[mb] = __builtin_amdgcn_mfma_f32_16x16x32_bf16(kA[mb], qB[nb], en[mb], 0, 0, 0);
      }
      float mx = en[0][0];
#pragma unroll
      for (int mb = 0; mb < 4; ++mb)
#pragma unroll
        for (int r = 0; r < 4; ++r) mx = fmaxf(mx, en[mb][r]);
      mx = fmaxf(mx, __shfl_xor(mx, 16));
      mx = fmaxf(mx, __shfl_xor(mx, 32));
      float p[4][4];
      float sum = 0.f;
#pragma unroll
      for (int mb = 0; mb < 4; ++mb)
#pragma unroll
        for (int r = 0; r < 4; ++r) {
          float t = __expf((en[mb][r] - mx) * 0.0625f);  // scale 1/sqrt(256)
          p[mb][r] = t;
          sum += t;
        }
      sum += __shfl_xor(sum, 16);
      sum += __shfl_xor(sum, 32);
      float rs = 1.0f / sum;
      uint32_t pk[4][2];
#pragma unroll
      for (int mb = 0; mb < 4; ++mb) {
        pk[mb][0] = pack_bf16(p[mb][0] * rs, p[mb][1] * rs);
        pk[mb][1] = pack_bf16(p[mb][2] * rs, p[mb][3] * rs);
      }
      f32x4 o0 = (f32x4){0.f, 0.f, 0.f, 0.f};
      f32x4 o1 = (f32x4){0.f, 0.f, 0.f, 0.f};
#pragma unroll
      for (int kk2 = 0; kk2 < 2; ++kk2) {
        s16x8 pA = xchg(pk[2 * kk2][0], pk[2 * kk2][1],
                        pk[2 * kk2 + 1][0], pk[2 * kk2 + 1][1], srcA, srcB, hisel);
        o0 = __builtin_amdgcn_mfma_f32_16x16x32_bf16(pA, vB[kk2][0], o0, 0, 0, 0);
        o1 = __builtin_amdgcn_mfma_f32_16x16x32_bf16(pA, vB[kk2][1], o1, 0, 0, 0);
      }
      // store o into xt: row = qtok, col = h*32 + 16t + l15 (x fully consumed)
#pragma unroll
      for (int r = 0; r < 4; ++r) {
        int row = 16 * (2 * s + nb) + 4 * l4 + r;
        uint32_t rsw = (uint32_t)(row & 7) << 4;
        uint32_t c0 = ((uint32_t)(row * 512 + (h * 32 + l15) * 2)) ^ rsw;
        uint32_t c1 = ((uint32_t)(row * 512 + (h * 32 + 16 + l15) * 2)) ^ rsw;
        *(unsigned short*)((char*)xt + c0) = f32_bf16(o0[r]);
        *(unsigned short*)((char*)xt + c1) = f32_bf16(o1[r]);
      }
    }
  }
  __syncthreads();

  // ---- out-projection: wave w -> out cols [w*16, w*16+16) ----
  {
    const int colbase = w * 16;
    const unsigned short* wobase = wout + (size_t)(colbase + l15) * 256 + l4 * 8;
    f32x4 acc[4];
#pragma unroll
    for (int m = 0; m < 4; ++m) acc[m] = (f32x4){0.f, 0.f, 0.f, 0.f};
#pragma unroll
    for (int kk = 0; kk < 8; ++kk) {
      s16x8 a4[4];
#pragma unroll
      for (int m = 0; m < 4; ++m) {
        uint32_t byte = ((uint32_t)((16 * m + l15) * 512 + kk * 64 + l4 * 16)) ^ xsw;
        a4[m] = *(const s16x8*)((const char*)xt + byte);
      }
      s16x8 wo = *(const s16x8*)(wobase + kk * 32);
#pragma unroll
      for (int m = 0; m < 4; ++m)
        acc[m] = __builtin_amdgcn_mfma_f32_16x16x32_bf16(a4[m], wo, acc[m], 0, 0, 0);
    }
    const float b = bias[colbase + l15];
    float* dst = out + (size_t)g * 64 * 256 + colbase + l15;
#pragma unroll
    for (int m = 0; m < 4; ++m)
#pragma unroll
      for (int r = 0; r < 4; ++r)
        dst[(size_t)(16 * m + 4 * l4 + r) * 256] = acc[m][r] + b;
  }
}

extern "C" void kernel_launch(void* const* d_in, const int* in_sizes, int n_in,
                              void* d_out, int out_size, void* d_ws, size_t ws_size,
                              hipStream_t stream) {
  const float* x    = (const float*)d_in[0];
  const float* wqkv = (const float*)d_in[1];
  const float* wout = (const float*)d_in[2];
  const float* bout = (const float*)d_in[3];
  float* out = (float*)d_out;

  unsigned short* wq_bf = (unsigned short*)d_ws;          // 768*256 bf16
  unsigned short* wo_bf = wq_bf + 768 * 256;              // 256*256 bf16

  convert_w<<<1024, 256, 0, stream>>>(wqkv, wout, wq_bf);
  mha_fused<<<2048, 1024, 0, stream>>>(x, wq_bf, wo_bf, bout, out);
}